// Round 18
// baseline (361.955 us; speedup 1.0000x reference)
//
#include <hip/hip_runtime.h>

// VQ-VAE vector quantizer, MI355X.
// e16 layout SLOT-MAJOR per 64-code chunk: [chunk][slot 0..31][code 0..63] x 16B.
// convert: emb->e16+e2, z->z16+z2 (numpy-exact), zero xmax-atomics + loss.
// pass1 (r16 exact, best measured 110.5us): 16x16x32 MFMA, 512 thr = 8 waves x 32
// pts, VGPR 64, LB(512,4); LDS-pipe bound (82us LDS vs 66us MFMA model).
// stageB: selection only (xmax from pass1 atomics). stageB2: buckets + zero ccnt
// (cmax lifetime!). stageC3: per-chunk blocks, e-rows in regs. mergeref2 (r18):
// phase-1 thread-per-point top-2 merge (parallelism preserved -- r15 lesson),
// flagged pts -> LDS queue; phase-2 wave-per-flagged numpy-bitwise re-decision
// (validated r3-r17) + fullscan. gather: fused loss atomicAdd.
typedef _Float16 half_t;
typedef _Float16 half8 __attribute__((ext_vector_type(8)));
typedef _Float16 half2_t __attribute__((ext_vector_type(2)));
typedef float f32x4 __attribute__((ext_vector_type(4)));
typedef unsigned long long ull;

#define K_CODES 8192
#define D_DIM   256
#define N_PTS   32768
#define HW      1024
#define CHW     262144
#define B_      32
#define W_      32

#define OFF_IDX  8388608
#define OFF_LOSS 8421376

#define KSPLIT 4
#define KRANGE 2048       // codes per by-split
#define NCHUNK 32         // 64-code chunks per split
#define W_WIN  1.5e-4f    // score-space near-tie window (validated r4-r17)
#define WX_SEL 0.63f      // x-space chunk cutoff: W_WIN*8192/2 = 0.6144 + slack
#define CAP_BKT 2048

// ws layout (bytes)
#define WS_E16  0x000000u // fp16 emb*8192, slot-major chunks, 4MB
#define WS_E2   0x400000u // f32[K] numpy-exact
#define WS_Z2   0x408000u // f32[N] numpy-exact
#define WS_SEL8 0x450000u // u64[N] packed chunk ids
#define WS_SCNT 0x490000u // i32[N]
#define WS_BCNT 0x4B2000u // u32[128] bucket counts + u32[1] fullscan count
// d_out overlays (bytes). LIFETIMES: cmax (0..16MB) live from pass1 until END of stageB.
// ent/ptop/cand/fslist/ccnt alias it but are written only from stageB2 onward.
// idx region: xmax atomics during pass1/stageB, final idx from mergeref2.
#define DO_CMAX  0x000000u  // f32[128][N] = 16MB    (pass1 -> stageB only)
#define DO_ENT   0x000000u  // u32[128][2048] = 1MB  (stageB2 -> stageC3)
#define DO_PTOP  0x100000u  // u64[N][8][2] = 4MB    (stageC3 -> mergeref2)
#define DO_CAND  0x500000u  // u32[N*32] = 4MB       (stageC3 -> mergeref2)
#define DO_FSCAN 0x900000u  // u32[N] overflow list  (unused by mergeref2; kept)
#define DO_CCNT  0x920000u  // u32[N]                (zeroed in stageB2)
#define DO_Z16   0x1000000u // half[N][256] = 16MB   (convert -> pass1/stageC3)

__device__ __forceinline__ unsigned int mono_enc(float f) {
    unsigned int u = __float_as_uint(f);
    return (u & 0x80000000u) ? ~u : (u | 0x80000000u);
}
__device__ __forceinline__ float mono_dec(unsigned int m) {
    unsigned int u = (m & 0x80000000u) ? (m ^ 0x80000000u) : ~m;
    return __uint_as_float(u);
}
__device__ __forceinline__ void glds16(const void* g, void* l) {
    __builtin_amdgcn_global_load_lds(
        (const __attribute__((address_space(1))) unsigned int*)g,
        (__attribute__((address_space(3))) unsigned int*)l, 16, 0, 0);
}

union u32h2 { unsigned int u; half2_t h; };
__device__ __forceinline__ half2_t h2(unsigned int u) { u32h2 t; t.u = u; return t.h; }

#if __has_builtin(__builtin_amdgcn_fdot2)
__device__ __forceinline__ float fdot2_(half2_t a, half2_t b, float c) {
    return __builtin_amdgcn_fdot2(a, b, c, false);
}
#else
__device__ __forceinline__ float fdot2_(half2_t a, half2_t b, float c) {
    return fmaf((float)a.x, (float)b.x, fmaf((float)a.y, (float)b.y, c));
}
#endif

__device__ __forceinline__ float red8np(const float* r) {
    return __fadd_rn(__fadd_rn(__fadd_rn(r[0], r[1]), __fadd_rn(r[2], r[3])),
                     __fadd_rn(__fadd_rn(r[4], r[5]), __fadd_rn(r[6], r[7])));
}

// convert: bx<32 -> emb path (e16 slot-major + numpy-exact e2);
//          bx>=32 -> z path (z16 + numpy-exact z2 + zero xmax atomic slot).
__global__ __launch_bounds__(256) void convert_kernel(
        const float* __restrict__ emb, char* __restrict__ e16, float* __restrict__ e2,
        const float* __restrict__ z, half_t* __restrict__ z16, float* __restrict__ z2,
        float* __restrict__ dout) {
    const int bx = blockIdx.x;
    if (bx < 32) {
        if (bx == 0 && threadIdx.x == 0) dout[OFF_LOSS] = 0.0f;
        const int k = bx * 256 + threadIdx.x;
        const float4* row = (const float4*)(emb + (size_t)k * D_DIM);
        char* dst = e16 + (size_t)(k >> 6) * 32768 + (size_t)(k & 63) * 16;
        float r[8], h1 = 0.f;
        #pragma unroll 4
        for (int s = 0; s < 32; s++) {
            if (s == 16) { h1 = red8np(r); }
            const float4 v0 = row[s * 2];
            const float4 v1 = row[s * 2 + 1];
            union { half_t h[8]; uint4 u; } t;
            t.h[0] = (half_t)(v0.x * 8192.0f); t.h[1] = (half_t)(v0.y * 8192.0f);
            t.h[2] = (half_t)(v0.z * 8192.0f); t.h[3] = (half_t)(v0.w * 8192.0f);
            t.h[4] = (half_t)(v1.x * 8192.0f); t.h[5] = (half_t)(v1.y * 8192.0f);
            t.h[6] = (half_t)(v1.z * 8192.0f); t.h[7] = (half_t)(v1.w * 8192.0f);
            *(uint4*)(dst + (size_t)s * 1024) = t.u;
            const float q0 = __fmul_rn(v0.x, v0.x), q1 = __fmul_rn(v0.y, v0.y);
            const float q2 = __fmul_rn(v0.z, v0.z), q3 = __fmul_rn(v0.w, v0.w);
            const float q4 = __fmul_rn(v1.x, v1.x), q5 = __fmul_rn(v1.y, v1.y);
            const float q6 = __fmul_rn(v1.z, v1.z), q7 = __fmul_rn(v1.w, v1.w);
            if (s == 0 || s == 16) {
                r[0] = q0; r[1] = q1; r[2] = q2; r[3] = q3;
                r[4] = q4; r[5] = q5; r[6] = q6; r[7] = q7;
            } else {
                r[0] = __fadd_rn(r[0], q0); r[1] = __fadd_rn(r[1], q1);
                r[2] = __fadd_rn(r[2], q2); r[3] = __fadd_rn(r[3], q3);
                r[4] = __fadd_rn(r[4], q4); r[5] = __fadd_rn(r[5], q5);
                r[6] = __fadd_rn(r[6], q6); r[7] = __fadd_rn(r[7], q7);
            }
        }
        e2[k] = __fadd_rn(h1, red8np(r));
    } else {
        const int pt = (bx - 32) * 256 + threadIdx.x;
        ((unsigned*)(dout + OFF_IDX))[pt] = 0u;   // xmax atomic init (mono min)
        const float* zp = z + (size_t)(pt >> 10) * CHW + (pt & (HW - 1));
        half_t* dst = z16 + (size_t)pt * 256;
        float hs[2];
        #pragma unroll
        for (int hb = 0; hb < 2; hb++) {
            float r[8];
            #pragma unroll
            for (int d0 = 0; d0 < 128; d0 += 8) {
                union { half_t h[8]; uint4 u; } t;
                #pragma unroll
                for (int j = 0; j < 8; j++) {
                    const float v = zp[(size_t)(hb * 128 + d0 + j) * HW];
                    t.h[j] = (half_t)v;
                    const float sq = __fmul_rn(v, v);
                    r[j] = (d0 == 0) ? sq : __fadd_rn(r[j], sq);
                }
                *(uint4*)(dst + hb * 128 + d0) = t.u;
            }
            hs[hb] = red8np(r);
        }
        z2[pt] = __fadd_rn(hs[0], hs[1]);
    }
}

// Pass-1 (r16 exact): dense fp16 16x16x32 MFMA GEMM + running-max atomics.
__global__ __launch_bounds__(512, 4) void pass1_kernel(
        const half_t* __restrict__ z16, const uint4* __restrict__ e16,
        float* __restrict__ cmax, unsigned* __restrict__ xatom) {
    __shared__ __align__(16) char sA[65536];   // 2 x 32KB code-tile double buffer
    const int tid  = threadIdx.x;
    const int lane = tid & 63;
    const int wave = tid >> 6;        // 0..7
    const int col  = lane & 15;
    const int quad = lane >> 4;
    const int bx = blockIdx.x, by = blockIdx.y;
    const int p0 = bx * 256;
    const int kbase = by * KRANGE;

    half8 zb[2][8];
    #pragma unroll
    for (int n = 0; n < 2; n++) {
        const int pt = p0 + wave * 32 + n * 16 + col;
        const char* src = (const char*)z16 + (size_t)pt * 512 + quad * 16;
        #pragma unroll
        for (int ks = 0; ks < 8; ks++)
            zb[n][ks] = *(const half8*)(src + ks * 64);
    }

    const char* esrc = (const char*)e16 + (size_t)kbase * 512;
    {
        const char* s0 = esrc + wave * 4096 + lane * 16;
        char* d0 = sA + wave * 4096;
        #pragma unroll
        for (int i = 0; i < 4; i++) glds16(s0 + i * 1024, d0 + i * 1024);
    }
    __syncthreads();

    float rmax[2] = {-3.0e38f, -3.0e38f};
    int cur = 0;
    for (int c = 0; c < NCHUNK; ++c) {
        if (c + 1 < NCHUNK) {
            const char* s0 = esrc + (size_t)(c + 1) * 32768 + wave * 4096 + lane * 16;
            char* d0 = sA + (cur ^ 1) * 32768 + wave * 4096;
            #pragma unroll
            for (int i = 0; i < 4; i++) glds16(s0 + i * 1024, d0 + i * 1024);
        }
        f32x4 acc[4][2];
        #pragma unroll
        for (int m = 0; m < 4; m++)
            #pragma unroll
            for (int n = 0; n < 2; n++) acc[m][n] = (f32x4){0.f, 0.f, 0.f, 0.f};

        const char* base = sA + cur * 32768 + col * 16;
        #pragma unroll
        for (int ks = 0; ks < 8; ks++) {
            const int so = (ks * 4 + quad) * 1024;   // slot-major: [slot][code]
            half8 a[4];
            #pragma unroll
            for (int m = 0; m < 4; m++) a[m] = *(const half8*)(base + so + m * 256);
            #pragma unroll
            for (int m = 0; m < 4; m++)
                #pragma unroll
                for (int n = 0; n < 2; n++)
                    acc[m][n] = __builtin_amdgcn_mfma_f32_16x16x32_f16(a[m], zb[n][ks], acc[m][n], 0, 0, 0);
        }
        const int sub = by * NCHUNK + c;
        #pragma unroll
        for (int n = 0; n < 2; n++) {
            float xm = acc[0][n][0];
            #pragma unroll
            for (int m = 0; m < 4; m++)
                #pragma unroll
                for (int r = 0; r < 4; r++) xm = fmaxf(xm, acc[m][n][r]);
            xm = fmaxf(xm, __shfl_xor(xm, 16, 64));
            xm = fmaxf(xm, __shfl_xor(xm, 32, 64));
            rmax[n] = fmaxf(rmax[n], xm);
            if (quad == 0)
                cmax[(size_t)sub * N_PTS + p0 + wave * 32 + n * 16 + col] = xm;
        }
        __syncthreads();
        cur ^= 1;
    }
    if (quad == 0) {
        #pragma unroll
        for (int n = 0; n < 2; n++)
            atomicMax(&xatom[p0 + wave * 32 + n * 16 + col], mono_enc(rmax[n]));
    }
}

// stageB: single selection pass (xmax from pass1 atomics); zero bucket counters
__global__ __launch_bounds__(256) void stageb_kernel(
        const float* __restrict__ cmax, const unsigned* __restrict__ xatom,
        ull* __restrict__ sel8, int* __restrict__ scnt, unsigned* __restrict__ bcnt) {
    if (threadIdx.x == 0) bcnt[blockIdx.x] = 0u;             // grid=128
    if (blockIdx.x == 0 && threadIdx.x == 1) bcnt[128] = 0u; // fullscan count
    const int pt = blockIdx.x * 256 + threadIdx.x;
    const float cut = mono_dec(xatom[pt]) - WX_SEL;
    ull pack = 0; int cnt = 0;
    for (int s = 0; s < 128; s++) {
        if (cmax[(size_t)s * N_PTS + pt] >= cut) {
            if (cnt < 8) pack |= ((ull)(unsigned)s) << (8 * cnt);
            cnt++;
        }
    }
    sel8[pt] = pack; scnt[pt] = cnt;
}

// stageB2: zero ccnt (cmax dead now); push (pt,j) into buckets; overflow/dense -> fullscan
__global__ __launch_bounds__(256) void stageb2_kernel(
        const ull* __restrict__ sel8, int* __restrict__ scnt,
        unsigned* __restrict__ bcnt, unsigned* __restrict__ ent,
        unsigned* __restrict__ fslist, unsigned* __restrict__ ccnt) {
    const int pt = blockIdx.x * 256 + threadIdx.x;
    ccnt[pt] = 0u;
    const int cnt = scnt[pt];
    bool ok = (cnt >= 1 && cnt <= 8);
    if (ok) {
        const ull s8 = sel8[pt];
        for (int j = 0; j < cnt; j++) {
            const int s = (int)((s8 >> (8 * j)) & 0xFFu);
            const unsigned pos = atomicAdd(&bcnt[s], 1u);
            if (pos >= CAP_BKT) { ok = false; break; }
            ent[s * CAP_BKT + pos] = (unsigned)pt | ((unsigned)j << 16);
        }
    }
    if (!ok) {
        const unsigned mp = atomicAdd(&bcnt[128], 1u);
        fslist[mp] = (unsigned)pt;
        scnt[pt] = -1;
    }
}

// stageC3: block-parts per chunk; e-rows in registers (coalesced slot-major loads),
// z broadcast via LDS. Per-(pt,chunk) top-2 -> ptop; superset candidates.
__global__ __launch_bounds__(256) void stagec3_kernel(
        const half_t* __restrict__ z16, const uint4* __restrict__ e16,
        const unsigned* __restrict__ bcnt, const unsigned* __restrict__ ent,
        ull* __restrict__ ptop, unsigned* __restrict__ cand,
        unsigned* __restrict__ ccnt) {
    __shared__ __align__(16) unsigned int zslot[4][128];   // per-wave 512B z row
    const int tid = threadIdx.x, lane = tid & 63, wave = tid >> 6;
    const int c = blockIdx.x & 127, part = blockIdx.x >> 7;
    const int npart = gridDim.x >> 7;
    const unsigned cnt = min(bcnt[c], (unsigned)CAP_BKT);
    if (cnt == 0) return;
    const int code = c * 64 + lane;
    uint4 e[32];
    {
        const uint4* er = e16 + (size_t)(code >> 6) * 2048 + (code & 63);
        #pragma unroll
        for (int j = 0; j < 32; j++) e[j] = er[(size_t)j * 64];
    }
    const char* zb = (const char*)&zslot[wave][0];
    for (unsigned i = (unsigned)(part * 4 + wave); i < cnt; i += (unsigned)(npart * 4)) {
        const unsigned ev = ent[c * CAP_BKT + i];
        const int pt = (int)(ev & 0xFFFFu);
        const int j  = (int)((ev >> 16) & 7u);
        {
            const uint2 w = *(const uint2*)((const char*)z16 + (size_t)pt * 512 + lane * 8);
            *(uint2*)((char*)&zslot[wave][0] + lane * 8) = w;
        }
        __threadfence_block();
        float x0 = 0.f, x1 = 0.f, x2 = 0.f, x3 = 0.f, x4 = 0.f, x5 = 0.f, x6 = 0.f, x7 = 0.f;
        #pragma unroll
        for (int q = 0; q < 32; q += 2) {
            const uint4 z0 = *(const uint4*)(zb + q * 16);
            const uint4 z1 = *(const uint4*)(zb + q * 16 + 16);
            x0 = fdot2_(h2(e[q].x),     h2(z0.x), x0);
            x1 = fdot2_(h2(e[q].y),     h2(z0.y), x1);
            x2 = fdot2_(h2(e[q].z),     h2(z0.z), x2);
            x3 = fdot2_(h2(e[q].w),     h2(z0.w), x3);
            x4 = fdot2_(h2(e[q + 1].x), h2(z1.x), x4);
            x5 = fdot2_(h2(e[q + 1].y), h2(z1.y), x5);
            x6 = fdot2_(h2(e[q + 1].z), h2(z1.z), x6);
            x7 = fdot2_(h2(e[q + 1].w), h2(z1.w), x7);
        }
        const float sc = (((x0 + x1) + (x2 + x3)) + ((x4 + x5) + (x6 + x7))) * (-2.0f / 8192.0f);
        ull r1 = ((ull)mono_enc(sc) << 32) | (unsigned)code;
        ull r2 = ~0ull;
        #pragma unroll
        for (int s = 1; s < 64; s <<= 1) {
            const ull o1 = __shfl_xor(r1, s, 64);
            const ull o2 = __shfl_xor(r2, s, 64);
            if (o1 < r1) { r2 = (r1 < o2) ? r1 : o2; r1 = o1; }
            else         { r2 = (o1 < r2) ? o1 : r2; }
        }
        if (lane == 0) {
            ptop[(size_t)(pt * 8 + j) * 2 + 0] = r1;
            ptop[(size_t)(pt * 8 + j) * 2 + 1] = r2;
        }
        const float v1 = mono_dec((unsigned)(r1 >> 32));
        const bool in = sc < v1 + W_WIN;
        const ull m = __ballot(in);
        int base = 0;
        if (lane == 0) base = (int)atomicAdd(&ccnt[pt], (unsigned)__popcll(m));
        base = __shfl(base, 0, 64);
        const int p = base + (int)__popcll(m & ((1ull << lane) - 1ull));
        if (in && p < 32) cand[(size_t)pt * 32 + p] = (unsigned)code;
    }
}

// mergeref2: phase-1 thread-per-point global top-2 (parallel), flagged -> LDS queue;
// phase-2 wave-per-flagged numpy-bitwise re-decision (validated) + fullscan.
__global__ __launch_bounds__(256) void mergeref2_kernel(
        const float* __restrict__ z, const float* __restrict__ emb,
        const float* __restrict__ e2, const float* __restrict__ z2,
        const ull* __restrict__ ptop, const int* __restrict__ scnt,
        const unsigned* __restrict__ cand, const unsigned* __restrict__ ccnt,
        float* __restrict__ dout) {
    __shared__ int qn;
    __shared__ int q[256];
    __shared__ float zl[4][256];
    const int tid = threadIdx.x, lane = tid & 63, wave = tid >> 6;
    const int pt = blockIdx.x * 256 + tid;
    if (tid == 0) qn = 0;
    __syncthreads();
    // phase 1: parallel merge
    const int cnt = scnt[pt];
    bool defer = false;
    if (cnt >= 1 && cnt <= 8) {
        ull b1 = ~0ull, b2 = ~0ull;
        for (int j = 0; j < cnt; j++) {
            #pragma unroll
            for (int t = 0; t < 2; t++) {
                const ull v = ptop[(size_t)(pt * 8 + j) * 2 + t];
                if (v < b1) { b2 = b1; b1 = v; } else if (v < b2) b2 = v;
            }
        }
        const float v1 = mono_dec((unsigned)(b1 >> 32));
        const float v2 = mono_dec((unsigned)(b2 >> 32));
        if (v2 - v1 >= W_WIN) {
            dout[OFF_IDX + pt] = (float)(unsigned)(b1 & 0xFFFFFFFFu);
        } else defer = true;
    } else defer = true;   // overflow/dense -> fullscan
    if (defer) {
        const int pos = atomicAdd(&qn, 1);
        q[pos] = pt;
    }
    __syncthreads();
    // phase 2: wave per deferred point
    const int nq = qn;
    for (int i = wave; i < nq; i += 4) {
        const int n = q[i];
        const float* zp = z + (size_t)(n >> 10) * CHW + (n & (HW - 1));
        #pragma unroll
        for (int u = 0; u < 4; u++)
            zl[wave][lane + 64 * u] = zp[(size_t)(lane + 64 * u) * HW];
        __threadfence_block();
        if (scnt[n] >= 1) {
            int cc = (int)ccnt[n]; if (cc > 32) cc = 32;
            float d; int k;
            if (lane < cc) {
                k = (int)cand[(size_t)n * 32 + lane];
                const float* ep = emb + (size_t)k * D_DIM;
                float m = 0.f;
                for (int c = 0; c < D_DIM; c++) m = fmaf(zl[wave][c], ep[c], m);
                d = __fsub_rn(__fadd_rn(z2[n], e2[k]), __fmul_rn(2.0f, m));
            } else { d = 3.0e38f; k = 1 << 20; }
            #pragma unroll
            for (int s = 1; s < 32; s <<= 1) {
                const float od = __shfl_xor(d, s, 64);
                const int   ok = __shfl_xor(k, s, 64);
                if (od < d || (od == d && ok < k)) { d = od; k = ok; }
            }
            if (lane == 0) dout[OFF_IDX + n] = (float)k;
        } else {
            float bd = 3.0e38f; int bk = 1 << 20;
            for (int t = 0; t < K_CODES / 64; t++) {
                const int k = t * 64 + lane;
                const float* ep = emb + (size_t)k * D_DIM;
                float m = 0.f;
                for (int c = 0; c < D_DIM; c++) m = fmaf(zl[wave][c], ep[c], m);
                const float d = __fsub_rn(__fadd_rn(z2[n], e2[k]), __fmul_rn(2.0f, m));
                if (d < bd) { bd = d; bk = k; }
            }
            #pragma unroll
            for (int s = 1; s < 64; s <<= 1) {
                const float od = __shfl_xor(bd, s, 64);
                const int   ok = __shfl_xor(bk, s, 64);
                if (od < bd || (od == bd && ok < bk)) { bd = od; bk = ok; }
            }
            if (lane == 0) dout[OFF_IDX + n] = (float)bk;
        }
    }
}

// gather emb[idx] -> (B,C,H,W) coalesced via LDS bounce; fused loss atomicAdd
__global__ __launch_bounds__(256) void gather_kernel(
        const float* __restrict__ z, const float* __restrict__ emb,
        float* __restrict__ dout) {
    __shared__ __align__(16) float qs[D_DIM][W_ + 1];
    __shared__ float red[4];
    const int bh = blockIdx.x;
    const int b = bh >> 5, h = bh & 31;
    const int tid = threadIdx.x;

    const float* idxf = dout + OFF_IDX + bh * W_;
    const int w  = tid >> 3;
    const int cq = tid & 7;
    const int idx_w = (int)idxf[w];
    const float* erow = emb + (size_t)idx_w * D_DIM;
    #pragma unroll
    for (int it = 0; it < 8; it++) {
        const int c4 = (it * 8 + cq) * 4;
        float4 v = *(const float4*)(erow + c4);
        qs[c4 + 0][w] = v.x; qs[c4 + 1][w] = v.y;
        qs[c4 + 2][w] = v.z; qs[c4 + 3][w] = v.w;
    }
    __syncthreads();

    const int w2 = tid & 31, cg = tid >> 5;
    float ss = 0.f;
    const float* zbh = z    + (size_t)b * CHW + h * W_;
    float*       obh = dout + (size_t)b * CHW + h * W_;
    #pragma unroll
    for (int it = 0; it < 32; it++) {
        const int c = cg * 32 + it;
        const float q  = qs[c][w2];
        const float zv = zbh[(size_t)c * HW + w2];
        obh[(size_t)c * HW + w2] = q;
        const float dd = q - zv;
        ss = fmaf(dd, dd, ss);
    }
    #pragma unroll
    for (int m = 1; m < 64; m <<= 1) ss += __shfl_xor(ss, m, 64);
    const int lane = tid & 63, wv = tid >> 6;
    if (lane == 0) red[wv] = ss;
    __syncthreads();
    if (tid == 0) {
        const float t = red[0] + red[1] + red[2] + red[3];
        atomicAdd(dout + OFF_LOSS, t * (1.25f / 8388608.0f));
    }
}

extern "C" void kernel_launch(void* const* d_in, const int* in_sizes, int n_in,
                              void* d_out, int out_size, void* d_ws, size_t ws_size,
                              hipStream_t stream) {
    const float* z   = (const float*)d_in[0];   // (32,256,32,32)
    const float* emb = (const float*)d_in[1];   // (8192,256)
    float* dout = (float*)d_out;

    char* ws  = (char*)d_ws;
    char* dob = (char*)d_out;
    uint4*  e16   = (uint4*)(ws + WS_E16);
    float*  e2    = (float*)(ws + WS_E2);
    float*  z2    = (float*)(ws + WS_Z2);
    ull*    sel8  = (ull*)(ws + WS_SEL8);
    int*    scnt  = (int*)(ws + WS_SCNT);
    unsigned* bcnt = (unsigned*)(ws + WS_BCNT);   // [0..127] buckets, [128] fullscan count
    float*    cmax  = (float*)(dob + DO_CMAX);
    half_t*   z16   = (half_t*)(dob + DO_Z16);
    unsigned* ent   = (unsigned*)(dob + DO_ENT);
    ull*      ptop  = (ull*)(dob + DO_PTOP);
    unsigned* cand  = (unsigned*)(dob + DO_CAND);
    unsigned* fslist= (unsigned*)(dob + DO_FSCAN);
    unsigned* ccnt  = (unsigned*)(dob + DO_CCNT);
    unsigned* xatom = (unsigned*)(dout + OFF_IDX);

    hipLaunchKernelGGL(convert_kernel,  dim3(160),         dim3(256), 0, stream, emb, (char*)e16, e2, z, z16, z2, dout);
    hipLaunchKernelGGL(pass1_kernel,    dim3(128, KSPLIT), dim3(512), 0, stream, z16, e16, cmax, xatom);
    hipLaunchKernelGGL(stageb_kernel,   dim3(128),         dim3(256), 0, stream, cmax, xatom, sel8, scnt, bcnt);
    hipLaunchKernelGGL(stageb2_kernel,  dim3(128),         dim3(256), 0, stream, sel8, scnt, bcnt, ent, fslist, ccnt);
    hipLaunchKernelGGL(stagec3_kernel,  dim3(1024),        dim3(256), 0, stream, z16, e16, bcnt, ent, ptop, cand, ccnt);
    hipLaunchKernelGGL(mergeref2_kernel,dim3(128),         dim3(256), 0, stream, z, emb, e2, z2, ptop, scnt, cand, ccnt, dout);
    hipLaunchKernelGGL(gather_kernel,   dim3(B_ * 32),     dim3(256), 0, stream, z, emb, dout);
}

// Round 19
// 292.869 us; speedup vs baseline: 1.2359x; 1.2359x over previous
//
#include <hip/hip_runtime.h>

// VQ-VAE vector quantizer, MI355X. (r19 = r16 verbatim + refine grid 1024)
// e16 layout SLOT-MAJOR per 64-code chunk: [chunk][slot 0..31][code 0..63] x 16B.
// convert: emb->e16+e2, z->z16+z2 (numpy-exact), zero xmax-atomics + loss.
// pass1: 16x16x32 MFMA + per-point running-max atomicMax (single-pass stageB).
// stageB: selection only. stageB2: buckets + zero ccnt (cmax lifetime!).
// stageC3: per-chunk blocks, e-rows in regs. mergeC: thread-per-point global top-2,
// flag near-ties (fused merge+refine twice measured latency-bound: r15 117us@6.6%occ,
// r18 114us@4.2%occ -- sparse path MUST have its own big-grid launch).
// refine: wave-per-FLAGGED-point numpy-bitwise re-decision (validated r3-r18) +
// fullscan. gather: fused loss atomicAdd.
typedef _Float16 half_t;
typedef _Float16 half8 __attribute__((ext_vector_type(8)));
typedef _Float16 half2_t __attribute__((ext_vector_type(2)));
typedef float f32x4 __attribute__((ext_vector_type(4)));
typedef unsigned long long ull;

#define K_CODES 8192
#define D_DIM   256
#define N_PTS   32768
#define HW      1024
#define CHW     262144
#define B_      32
#define W_      32

#define OFF_IDX  8388608
#define OFF_LOSS 8421376

#define KSPLIT 4
#define KRANGE 2048       // codes per by-split
#define NCHUNK 32         // 64-code chunks per split
#define W_WIN  1.5e-4f    // score-space near-tie window (validated r4-r18)
#define WX_SEL 0.63f      // x-space chunk cutoff: W_WIN*8192/2 = 0.6144 + slack
#define CAP_BKT 2048

// ws layout (bytes)
#define WS_E16  0x000000u // fp16 emb*8192, slot-major chunks, 4MB
#define WS_E2   0x400000u // f32[K] numpy-exact
#define WS_Z2   0x408000u // f32[N] numpy-exact
#define WS_FLAG 0x428000u // count + flagged-point list
#define WS_SEL8 0x450000u // u64[N] packed chunk ids
#define WS_SCNT 0x490000u // i32[N]
#define WS_BCNT 0x4B2000u // u32[128] bucket counts + u32[1] fullscan count
// d_out overlays (bytes). LIFETIMES: cmax (0..16MB) live from pass1 until END of stageB.
// ent/ptop/cand/fslist/ccnt alias it but are written only from stageB2 onward.
// idx region: xmax atomics during pass1/stageB, final idx from mergeC/refine.
#define DO_CMAX  0x000000u  // f32[128][N] = 16MB    (pass1 -> stageB only)
#define DO_ENT   0x000000u  // u32[128][2048] = 1MB  (stageB2 -> stageC3)
#define DO_PTOP  0x100000u  // u64[N][8][2] = 4MB    (stageC3 -> mergeC)
#define DO_CAND  0x500000u  // u32[N*32] = 4MB       (stageC3 -> refine)
#define DO_FSCAN 0x900000u  // u32[N] overflow list  (stageB2 -> refine)
#define DO_CCNT  0x920000u  // u32[N]                (zeroed in stageB2)
#define DO_Z16   0x1000000u // half[N][256] = 16MB   (convert -> pass1/stageC3)

__device__ __forceinline__ unsigned int mono_enc(float f) {
    unsigned int u = __float_as_uint(f);
    return (u & 0x80000000u) ? ~u : (u | 0x80000000u);
}
__device__ __forceinline__ float mono_dec(unsigned int m) {
    unsigned int u = (m & 0x80000000u) ? (m ^ 0x80000000u) : ~m;
    return __uint_as_float(u);
}
__device__ __forceinline__ void glds16(const void* g, void* l) {
    __builtin_amdgcn_global_load_lds(
        (const __attribute__((address_space(1))) unsigned int*)g,
        (__attribute__((address_space(3))) unsigned int*)l, 16, 0, 0);
}

union u32h2 { unsigned int u; half2_t h; };
__device__ __forceinline__ half2_t h2(unsigned int u) { u32h2 t; t.u = u; return t.h; }

#if __has_builtin(__builtin_amdgcn_fdot2)
__device__ __forceinline__ float fdot2_(half2_t a, half2_t b, float c) {
    return __builtin_amdgcn_fdot2(a, b, c, false);
}
#else
__device__ __forceinline__ float fdot2_(half2_t a, half2_t b, float c) {
    return fmaf((float)a.x, (float)b.x, fmaf((float)a.y, (float)b.y, c));
}
#endif

__device__ __forceinline__ float red8np(const float* r) {
    return __fadd_rn(__fadd_rn(__fadd_rn(r[0], r[1]), __fadd_rn(r[2], r[3])),
                     __fadd_rn(__fadd_rn(r[4], r[5]), __fadd_rn(r[6], r[7])));
}

// convert: bx<32 -> emb path (e16 slot-major + numpy-exact e2);
//          bx>=32 -> z path (z16 + numpy-exact z2 + zero xmax atomic slot).
__global__ __launch_bounds__(256) void convert_kernel(
        const float* __restrict__ emb, char* __restrict__ e16, float* __restrict__ e2,
        const float* __restrict__ z, half_t* __restrict__ z16, float* __restrict__ z2,
        float* __restrict__ dout, int* __restrict__ flags) {
    const int bx = blockIdx.x;
    if (bx < 32) {
        if (bx == 0 && threadIdx.x == 0) { dout[OFF_LOSS] = 0.0f; flags[0] = 0; }
        const int k = bx * 256 + threadIdx.x;
        const float4* row = (const float4*)(emb + (size_t)k * D_DIM);
        char* dst = e16 + (size_t)(k >> 6) * 32768 + (size_t)(k & 63) * 16;
        float r[8], h1 = 0.f;
        #pragma unroll 4
        for (int s = 0; s < 32; s++) {
            if (s == 16) { h1 = red8np(r); }
            const float4 v0 = row[s * 2];
            const float4 v1 = row[s * 2 + 1];
            union { half_t h[8]; uint4 u; } t;
            t.h[0] = (half_t)(v0.x * 8192.0f); t.h[1] = (half_t)(v0.y * 8192.0f);
            t.h[2] = (half_t)(v0.z * 8192.0f); t.h[3] = (half_t)(v0.w * 8192.0f);
            t.h[4] = (half_t)(v1.x * 8192.0f); t.h[5] = (half_t)(v1.y * 8192.0f);
            t.h[6] = (half_t)(v1.z * 8192.0f); t.h[7] = (half_t)(v1.w * 8192.0f);
            *(uint4*)(dst + (size_t)s * 1024) = t.u;
            const float q0 = __fmul_rn(v0.x, v0.x), q1 = __fmul_rn(v0.y, v0.y);
            const float q2 = __fmul_rn(v0.z, v0.z), q3 = __fmul_rn(v0.w, v0.w);
            const float q4 = __fmul_rn(v1.x, v1.x), q5 = __fmul_rn(v1.y, v1.y);
            const float q6 = __fmul_rn(v1.z, v1.z), q7 = __fmul_rn(v1.w, v1.w);
            if (s == 0 || s == 16) {
                r[0] = q0; r[1] = q1; r[2] = q2; r[3] = q3;
                r[4] = q4; r[5] = q5; r[6] = q6; r[7] = q7;
            } else {
                r[0] = __fadd_rn(r[0], q0); r[1] = __fadd_rn(r[1], q1);
                r[2] = __fadd_rn(r[2], q2); r[3] = __fadd_rn(r[3], q3);
                r[4] = __fadd_rn(r[4], q4); r[5] = __fadd_rn(r[5], q5);
                r[6] = __fadd_rn(r[6], q6); r[7] = __fadd_rn(r[7], q7);
            }
        }
        e2[k] = __fadd_rn(h1, red8np(r));
    } else {
        const int pt = (bx - 32) * 256 + threadIdx.x;
        ((unsigned*)(dout + OFF_IDX))[pt] = 0u;   // xmax atomic init (mono min)
        const float* zp = z + (size_t)(pt >> 10) * CHW + (pt & (HW - 1));
        half_t* dst = z16 + (size_t)pt * 256;
        float hs[2];
        #pragma unroll
        for (int hb = 0; hb < 2; hb++) {
            float r[8];
            #pragma unroll
            for (int d0 = 0; d0 < 128; d0 += 8) {
                union { half_t h[8]; uint4 u; } t;
                #pragma unroll
                for (int j = 0; j < 8; j++) {
                    const float v = zp[(size_t)(hb * 128 + d0 + j) * HW];
                    t.h[j] = (half_t)v;
                    const float sq = __fmul_rn(v, v);
                    r[j] = (d0 == 0) ? sq : __fadd_rn(r[j], sq);
                }
                *(uint4*)(dst + hb * 128 + d0) = t.u;
            }
            hs[hb] = red8np(r);
        }
        z2[pt] = __fadd_rn(hs[0], hs[1]);
    }
}

// Pass-1: dense fp16 16x16x32 MFMA GEMM + running-max atomics.
__global__ __launch_bounds__(512, 4) void pass1_kernel(
        const half_t* __restrict__ z16, const uint4* __restrict__ e16,
        float* __restrict__ cmax, unsigned* __restrict__ xatom) {
    __shared__ __align__(16) char sA[65536];   // 2 x 32KB code-tile double buffer
    const int tid  = threadIdx.x;
    const int lane = tid & 63;
    const int wave = tid >> 6;        // 0..7
    const int col  = lane & 15;
    const int quad = lane >> 4;
    const int bx = blockIdx.x, by = blockIdx.y;
    const int p0 = bx * 256;
    const int kbase = by * KRANGE;

    half8 zb[2][8];
    #pragma unroll
    for (int n = 0; n < 2; n++) {
        const int pt = p0 + wave * 32 + n * 16 + col;
        const char* src = (const char*)z16 + (size_t)pt * 512 + quad * 16;
        #pragma unroll
        for (int ks = 0; ks < 8; ks++)
            zb[n][ks] = *(const half8*)(src + ks * 64);
    }

    const char* esrc = (const char*)e16 + (size_t)kbase * 512;
    {
        const char* s0 = esrc + wave * 4096 + lane * 16;
        char* d0 = sA + wave * 4096;
        #pragma unroll
        for (int i = 0; i < 4; i++) glds16(s0 + i * 1024, d0 + i * 1024);
    }
    __syncthreads();

    float rmax[2] = {-3.0e38f, -3.0e38f};
    int cur = 0;
    for (int c = 0; c < NCHUNK; ++c) {
        if (c + 1 < NCHUNK) {
            const char* s0 = esrc + (size_t)(c + 1) * 32768 + wave * 4096 + lane * 16;
            char* d0 = sA + (cur ^ 1) * 32768 + wave * 4096;
            #pragma unroll
            for (int i = 0; i < 4; i++) glds16(s0 + i * 1024, d0 + i * 1024);
        }
        f32x4 acc[4][2];
        #pragma unroll
        for (int m = 0; m < 4; m++)
            #pragma unroll
            for (int n = 0; n < 2; n++) acc[m][n] = (f32x4){0.f, 0.f, 0.f, 0.f};

        const char* base = sA + cur * 32768 + col * 16;
        #pragma unroll
        for (int ks = 0; ks < 8; ks++) {
            const int so = (ks * 4 + quad) * 1024;   // slot-major: [slot][code]
            half8 a[4];
            #pragma unroll
            for (int m = 0; m < 4; m++) a[m] = *(const half8*)(base + so + m * 256);
            #pragma unroll
            for (int m = 0; m < 4; m++)
                #pragma unroll
                for (int n = 0; n < 2; n++)
                    acc[m][n] = __builtin_amdgcn_mfma_f32_16x16x32_f16(a[m], zb[n][ks], acc[m][n], 0, 0, 0);
        }
        const int sub = by * NCHUNK + c;
        #pragma unroll
        for (int n = 0; n < 2; n++) {
            float xm = acc[0][n][0];
            #pragma unroll
            for (int m = 0; m < 4; m++)
                #pragma unroll
                for (int r = 0; r < 4; r++) xm = fmaxf(xm, acc[m][n][r]);
            xm = fmaxf(xm, __shfl_xor(xm, 16, 64));
            xm = fmaxf(xm, __shfl_xor(xm, 32, 64));
            rmax[n] = fmaxf(rmax[n], xm);
            if (quad == 0)
                cmax[(size_t)sub * N_PTS + p0 + wave * 32 + n * 16 + col] = xm;
        }
        __syncthreads();
        cur ^= 1;
    }
    if (quad == 0) {
        #pragma unroll
        for (int n = 0; n < 2; n++)
            atomicMax(&xatom[p0 + wave * 32 + n * 16 + col], mono_enc(rmax[n]));
    }
}

// stageB: single selection pass (xmax from pass1 atomics); zero bucket counters
__global__ __launch_bounds__(256) void stageb_kernel(
        const float* __restrict__ cmax, const unsigned* __restrict__ xatom,
        ull* __restrict__ sel8, int* __restrict__ scnt, unsigned* __restrict__ bcnt) {
    if (threadIdx.x == 0) bcnt[blockIdx.x] = 0u;             // grid=128
    if (blockIdx.x == 0 && threadIdx.x == 1) bcnt[128] = 0u; // fullscan count
    const int pt = blockIdx.x * 256 + threadIdx.x;
    const float cut = mono_dec(xatom[pt]) - WX_SEL;
    ull pack = 0; int cnt = 0;
    for (int s = 0; s < 128; s++) {
        if (cmax[(size_t)s * N_PTS + pt] >= cut) {
            if (cnt < 8) pack |= ((ull)(unsigned)s) << (8 * cnt);
            cnt++;
        }
    }
    sel8[pt] = pack; scnt[pt] = cnt;
}

// stageB2: zero ccnt (cmax dead now); push (pt,j) into buckets; overflow/dense -> fullscan
__global__ __launch_bounds__(256) void stageb2_kernel(
        const ull* __restrict__ sel8, int* __restrict__ scnt,
        unsigned* __restrict__ bcnt, unsigned* __restrict__ ent,
        unsigned* __restrict__ fslist, unsigned* __restrict__ ccnt) {
    const int pt = blockIdx.x * 256 + threadIdx.x;
    ccnt[pt] = 0u;
    const int cnt = scnt[pt];
    bool ok = (cnt >= 1 && cnt <= 8);
    if (ok) {
        const ull s8 = sel8[pt];
        for (int j = 0; j < cnt; j++) {
            const int s = (int)((s8 >> (8 * j)) & 0xFFu);
            const unsigned pos = atomicAdd(&bcnt[s], 1u);
            if (pos >= CAP_BKT) { ok = false; break; }
            ent[s * CAP_BKT + pos] = (unsigned)pt | ((unsigned)j << 16);
        }
    }
    if (!ok) {
        const unsigned mp = atomicAdd(&bcnt[128], 1u);
        fslist[mp] = (unsigned)pt;
        scnt[pt] = -1;
    }
}

// stageC3: block-parts per chunk; e-rows in registers (coalesced slot-major loads),
// z broadcast via LDS. Per-(pt,chunk) top-2 -> ptop; superset candidates.
__global__ __launch_bounds__(256) void stagec3_kernel(
        const half_t* __restrict__ z16, const uint4* __restrict__ e16,
        const unsigned* __restrict__ bcnt, const unsigned* __restrict__ ent,
        ull* __restrict__ ptop, unsigned* __restrict__ cand,
        unsigned* __restrict__ ccnt) {
    __shared__ __align__(16) unsigned int zslot[4][128];   // per-wave 512B z row
    const int tid = threadIdx.x, lane = tid & 63, wave = tid >> 6;
    const int c = blockIdx.x & 127, part = blockIdx.x >> 7;
    const int npart = gridDim.x >> 7;
    const unsigned cnt = min(bcnt[c], (unsigned)CAP_BKT);
    if (cnt == 0) return;
    const int code = c * 64 + lane;
    uint4 e[32];
    {
        const uint4* er = e16 + (size_t)(code >> 6) * 2048 + (code & 63);
        #pragma unroll
        for (int j = 0; j < 32; j++) e[j] = er[(size_t)j * 64];
    }
    const char* zb = (const char*)&zslot[wave][0];
    for (unsigned i = (unsigned)(part * 4 + wave); i < cnt; i += (unsigned)(npart * 4)) {
        const unsigned ev = ent[c * CAP_BKT + i];
        const int pt = (int)(ev & 0xFFFFu);
        const int j  = (int)((ev >> 16) & 7u);
        {
            const uint2 w = *(const uint2*)((const char*)z16 + (size_t)pt * 512 + lane * 8);
            *(uint2*)((char*)&zslot[wave][0] + lane * 8) = w;
        }
        __threadfence_block();
        float x0 = 0.f, x1 = 0.f, x2 = 0.f, x3 = 0.f, x4 = 0.f, x5 = 0.f, x6 = 0.f, x7 = 0.f;
        #pragma unroll
        for (int q = 0; q < 32; q += 2) {
            const uint4 z0 = *(const uint4*)(zb + q * 16);
            const uint4 z1 = *(const uint4*)(zb + q * 16 + 16);
            x0 = fdot2_(h2(e[q].x),     h2(z0.x), x0);
            x1 = fdot2_(h2(e[q].y),     h2(z0.y), x1);
            x2 = fdot2_(h2(e[q].z),     h2(z0.z), x2);
            x3 = fdot2_(h2(e[q].w),     h2(z0.w), x3);
            x4 = fdot2_(h2(e[q + 1].x), h2(z1.x), x4);
            x5 = fdot2_(h2(e[q + 1].y), h2(z1.y), x5);
            x6 = fdot2_(h2(e[q + 1].z), h2(z1.z), x6);
            x7 = fdot2_(h2(e[q + 1].w), h2(z1.w), x7);
        }
        const float sc = (((x0 + x1) + (x2 + x3)) + ((x4 + x5) + (x6 + x7))) * (-2.0f / 8192.0f);
        ull r1 = ((ull)mono_enc(sc) << 32) | (unsigned)code;
        ull r2 = ~0ull;
        #pragma unroll
        for (int s = 1; s < 64; s <<= 1) {
            const ull o1 = __shfl_xor(r1, s, 64);
            const ull o2 = __shfl_xor(r2, s, 64);
            if (o1 < r1) { r2 = (r1 < o2) ? r1 : o2; r1 = o1; }
            else         { r2 = (o1 < r2) ? o1 : r2; }
        }
        if (lane == 0) {
            ptop[(size_t)(pt * 8 + j) * 2 + 0] = r1;
            ptop[(size_t)(pt * 8 + j) * 2 + 1] = r2;
        }
        const float v1 = mono_dec((unsigned)(r1 >> 32));
        const bool in = sc < v1 + W_WIN;
        const ull m = __ballot(in);
        int base = 0;
        if (lane == 0) base = (int)atomicAdd(&ccnt[pt], (unsigned)__popcll(m));
        base = __shfl(base, 0, 64);
        const int p = base + (int)__popcll(m & ((1ull << lane) - 1ull));
        if (in && p < 32) cand[(size_t)pt * 32 + p] = (unsigned)code;
    }
}

// mergeC: thread-per-point global top-2 over <=8 pairs; write idx or flag near-tie
__global__ __launch_bounds__(256) void mergec_kernel(
        const ull* __restrict__ ptop, const int* __restrict__ scnt,
        int* __restrict__ flags, float* __restrict__ dout) {
    const int pt = blockIdx.x * 256 + threadIdx.x;
    const int cnt = scnt[pt];
    if (cnt < 1 || cnt > 8) return;   // refine's fullscan handles
    ull b1 = ~0ull, b2 = ~0ull;
    for (int j = 0; j < cnt; j++) {
        #pragma unroll
        for (int t = 0; t < 2; t++) {
            const ull v = ptop[(size_t)(pt * 8 + j) * 2 + t];
            if (v < b1) { b2 = b1; b1 = v; } else if (v < b2) b2 = v;
        }
    }
    dout[OFF_IDX + pt] = (float)(unsigned)(b1 & 0xFFFFFFFFu);
    const float v1 = mono_dec((unsigned)(b1 >> 32));
    const float v2 = mono_dec((unsigned)(b2 >> 32));
    if (v2 - v1 < W_WIN) {
        const int pos = atomicAdd(flags, 1);
        flags[16 + pos] = pt;
    }
}

// refine: wave-per-flagged-point numpy-bitwise re-decision (z staged in LDS,
// bit-identical chain) + fullscan fallback for overflow points.
__global__ __launch_bounds__(256) void refine_kernel(
        const float* __restrict__ z, const float* __restrict__ emb,
        const float* __restrict__ e2, const float* __restrict__ z2,
        const unsigned* __restrict__ cand, const unsigned* __restrict__ candcnt,
        const int* __restrict__ flags, const unsigned* __restrict__ fslist,
        const unsigned* __restrict__ bcnt, float* __restrict__ dout) {
    __shared__ float zl[4][256];
    const int tid = threadIdx.x, lane = tid & 63, wave = tid >> 6;
    const int gw = blockIdx.x * 4 + wave;
    const int nw = gridDim.x * 4;
    const int count = flags[0];
    for (int f = gw; f < count; f += nw) {
        const int n = flags[16 + f];
        const float* zp = z + (size_t)(n >> 10) * CHW + (n & (HW - 1));
        #pragma unroll
        for (int q = 0; q < 4; q++)
            zl[wave][lane + 64 * q] = zp[(size_t)(lane + 64 * q) * HW];
        __threadfence_block();
        int cc = (int)candcnt[n]; if (cc > 32) cc = 32;
        float d; int k;
        if (lane < cc) {
            k = (int)cand[(size_t)n * 32 + lane];
            const float* ep = emb + (size_t)k * D_DIM;
            float m = 0.f;
            for (int c = 0; c < D_DIM; c++) m = fmaf(zl[wave][c], ep[c], m);
            d = __fsub_rn(__fadd_rn(z2[n], e2[k]), __fmul_rn(2.0f, m));
        } else { d = 3.0e38f; k = 1 << 20; }
        #pragma unroll
        for (int s = 1; s < 32; s <<= 1) {
            const float od = __shfl_xor(d, s, 64);
            const int   ok = __shfl_xor(k, s, 64);
            if (od < d || (od == d && ok < k)) { d = od; k = ok; }
        }
        if (lane == 0) dout[OFF_IDX + n] = (float)k;
    }
    const int fscount = (int)bcnt[128];
    for (int f = gw; f < fscount; f += nw) {
        const int n = (int)fslist[f];
        const float* zp = z + (size_t)(n >> 10) * CHW + (n & (HW - 1));
        #pragma unroll
        for (int q = 0; q < 4; q++)
            zl[wave][lane + 64 * q] = zp[(size_t)(lane + 64 * q) * HW];
        __threadfence_block();
        float bd = 3.0e38f; int bk = 1 << 20;
        for (int t = 0; t < K_CODES / 64; t++) {
            const int k = t * 64 + lane;
            const float* ep = emb + (size_t)k * D_DIM;
            float m = 0.f;
            for (int c = 0; c < D_DIM; c++) m = fmaf(zl[wave][c], ep[c], m);
            const float d = __fsub_rn(__fadd_rn(z2[n], e2[k]), __fmul_rn(2.0f, m));
            if (d < bd) { bd = d; bk = k; }
        }
        #pragma unroll
        for (int s = 1; s < 64; s <<= 1) {
            const float od = __shfl_xor(bd, s, 64);
            const int   ok = __shfl_xor(bk, s, 64);
            if (od < bd || (od == bd && ok < bk)) { bd = od; bk = ok; }
        }
        if (lane == 0) dout[OFF_IDX + n] = (float)bk;
    }
}

// gather emb[idx] -> (B,C,H,W) coalesced via LDS bounce; fused loss atomicAdd
__global__ __launch_bounds__(256) void gather_kernel(
        const float* __restrict__ z, const float* __restrict__ emb,
        float* __restrict__ dout) {
    __shared__ __align__(16) float qs[D_DIM][W_ + 1];
    __shared__ float red[4];
    const int bh = blockIdx.x;
    const int b = bh >> 5, h = bh & 31;
    const int tid = threadIdx.x;

    const float* idxf = dout + OFF_IDX + bh * W_;
    const int w  = tid >> 3;
    const int cq = tid & 7;
    const int idx_w = (int)idxf[w];
    const float* erow = emb + (size_t)idx_w * D_DIM;
    #pragma unroll
    for (int it = 0; it < 8; it++) {
        const int c4 = (it * 8 + cq) * 4;
        float4 v = *(const float4*)(erow + c4);
        qs[c4 + 0][w] = v.x; qs[c4 + 1][w] = v.y;
        qs[c4 + 2][w] = v.z; qs[c4 + 3][w] = v.w;
    }
    __syncthreads();

    const int w2 = tid & 31, cg = tid >> 5;
    float ss = 0.f;
    const float* zbh = z    + (size_t)b * CHW + h * W_;
    float*       obh = dout + (size_t)b * CHW + h * W_;
    #pragma unroll
    for (int it = 0; it < 32; it++) {
        const int c = cg * 32 + it;
        const float q  = qs[c][w2];
        const float zv = zbh[(size_t)c * HW + w2];
        obh[(size_t)c * HW + w2] = q;
        const float dd = q - zv;
        ss = fmaf(dd, dd, ss);
    }
    #pragma unroll
    for (int m = 1; m < 64; m <<= 1) ss += __shfl_xor(ss, m, 64);
    const int lane = tid & 63, wv = tid >> 6;
    if (lane == 0) red[wv] = ss;
    __syncthreads();
    if (tid == 0) {
        const float t = red[0] + red[1] + red[2] + red[3];
        atomicAdd(dout + OFF_LOSS, t * (1.25f / 8388608.0f));
    }
}

extern "C" void kernel_launch(void* const* d_in, const int* in_sizes, int n_in,
                              void* d_out, int out_size, void* d_ws, size_t ws_size,
                              hipStream_t stream) {
    const float* z   = (const float*)d_in[0];   // (32,256,32,32)
    const float* emb = (const float*)d_in[1];   // (8192,256)
    float* dout = (float*)d_out;

    char* ws  = (char*)d_ws;
    char* dob = (char*)d_out;
    uint4*  e16   = (uint4*)(ws + WS_E16);
    float*  e2    = (float*)(ws + WS_E2);
    float*  z2    = (float*)(ws + WS_Z2);
    int*    flags = (int*)(ws + WS_FLAG);
    ull*    sel8  = (ull*)(ws + WS_SEL8);
    int*    scnt  = (int*)(ws + WS_SCNT);
    unsigned* bcnt = (unsigned*)(ws + WS_BCNT);   // [0..127] buckets, [128] fullscan count
    float*    cmax  = (float*)(dob + DO_CMAX);
    half_t*   z16   = (half_t*)(dob + DO_Z16);
    unsigned* ent   = (unsigned*)(dob + DO_ENT);
    ull*      ptop  = (ull*)(dob + DO_PTOP);
    unsigned* cand  = (unsigned*)(dob + DO_CAND);
    unsigned* fslist= (unsigned*)(dob + DO_FSCAN);
    unsigned* ccnt  = (unsigned*)(dob + DO_CCNT);
    unsigned* xatom = (unsigned*)(dout + OFF_IDX);

    hipLaunchKernelGGL(convert_kernel, dim3(160),         dim3(256), 0, stream, emb, (char*)e16, e2, z, z16, z2, dout, flags);
    hipLaunchKernelGGL(pass1_kernel,   dim3(128, KSPLIT), dim3(512), 0, stream, z16, e16, cmax, xatom);
    hipLaunchKernelGGL(stageb_kernel,  dim3(128),         dim3(256), 0, stream, cmax, xatom, sel8, scnt, bcnt);
    hipLaunchKernelGGL(stageb2_kernel, dim3(128),         dim3(256), 0, stream, sel8, scnt, bcnt, ent, fslist, ccnt);
    hipLaunchKernelGGL(stagec3_kernel, dim3(1024),        dim3(256), 0, stream, z16, e16, bcnt, ent, ptop, cand, ccnt);
    hipLaunchKernelGGL(mergec_kernel,  dim3(128),         dim3(256), 0, stream, ptop, scnt, flags, dout);
    hipLaunchKernelGGL(refine_kernel,  dim3(1024),        dim3(256), 0, stream, z, emb, e2, z2, cand, ccnt, flags, fslist, bcnt, dout);
    hipLaunchKernelGGL(gather_kernel,  dim3(B_ * 32),     dim3(256), 0, stream, z, emb, dout);
}